// Round 6
// baseline (144.488 us; speedup 1.0000x reference)
//
#include <hip/hip_runtime.h>

typedef __bf16 bf16_t;
typedef bf16_t bf16x8 __attribute__((ext_vector_type(8)));
typedef bf16_t bf16x4 __attribute__((ext_vector_type(4)));
typedef float f32x4 __attribute__((ext_vector_type(4)));

__device__ __forceinline__ void gload_lds16(const bf16_t* g, bf16_t* l) {
    __builtin_amdgcn_global_load_lds(
        (const __attribute__((address_space(1))) void*)g,
        (__attribute__((address_space(3))) void*)l, 16, 0, 0);
}

// ---------------- fp32 -> bf16 convert (both weight matrices, one launch) ----------------
__global__ __launch_bounds__(256) void cvt_bf16_kernel(const float* __restrict__ in1,
                                                       const float* __restrict__ in2,
                                                       bf16_t* __restrict__ out1,
                                                       bf16_t* __restrict__ out2,
                                                       int n1_4, int ntot_4) {
    int i = blockIdx.x * 256 + threadIdx.x;
    if (i >= ntot_4) return;
    const float* in = (i < n1_4) ? in1 : in2;
    bf16_t* out = (i < n1_4) ? out1 : out2;
    int j = (i < n1_4) ? i : i - n1_4;
    float4 v = reinterpret_cast<const float4*>(in)[j];
    bf16x4 o;
    o[0] = (bf16_t)v.x; o[1] = (bf16_t)v.y; o[2] = (bf16_t)v.z; o[3] = (bf16_t)v.w;
    *reinterpret_cast<bf16x4*>(out + (size_t)j * 4) = o;
}

// ---------------- GroupNorm over dim1 groups ----------------
__global__ __launch_bounds__(256) void groupnorm_kernel(const float* __restrict__ x,
        const float* __restrict__ gw, const float* __restrict__ gb,
        bf16_t* __restrict__ h) {
    int bg = blockIdx.x;
    int batch = bg >> 5, g = bg & 31;
    const float* xp = x + ((size_t)batch * 1024 + g * 32) * 1024;
    float s = 0.f, s2 = 0.f;
    for (int i = threadIdx.x; i < 8192; i += 256) {
        float4 v = reinterpret_cast<const float4*>(xp)[i];
        s  += v.x + v.y + v.z + v.w;
        s2 += v.x*v.x + v.y*v.y + v.z*v.z + v.w*v.w;
    }
    #pragma unroll
    for (int o = 32; o >= 1; o >>= 1) {
        s  += __shfl_down(s, o, 64);
        s2 += __shfl_down(s2, o, 64);
    }
    __shared__ float ps[4], ps2[4];
    __shared__ float stat[2];
    if ((threadIdx.x & 63) == 0) { ps[threadIdx.x >> 6] = s; ps2[threadIdx.x >> 6] = s2; }
    __syncthreads();
    if (threadIdx.x == 0) {
        float S  = ps[0] + ps[1] + ps[2] + ps[3];
        float S2 = ps2[0] + ps2[1] + ps2[2] + ps2[3];
        float mu  = S * (1.f / 32768.f);
        float var = S2 * (1.f / 32768.f) - mu * mu;
        stat[0] = mu; stat[1] = rsqrtf(var + 1e-6f);
    }
    __syncthreads();
    float mu = stat[0], rs = stat[1];
    bf16_t* hp = h + ((size_t)batch * 1024 + g * 32) * 1024;
    for (int i = threadIdx.x; i < 8192; i += 256) {
        float4 v = reinterpret_cast<const float4*>(xp)[i];
        int row = i >> 8;
        float a = rs * gw[g * 32 + row];
        float b = gb[g * 32 + row] - mu * a;
        bf16x4 o;
        o[0] = (bf16_t)(v.x * a + b); o[1] = (bf16_t)(v.y * a + b);
        o[2] = (bf16_t)(v.z * a + b); o[3] = (bf16_t)(v.w * a + b);
        *reinterpret_cast<bf16x4*>(hp + (size_t)i * 4) = o;
    }
}

// ---------------- bf16 MFMA GEMM (m97 structure): C = A @ W^T (+bias[,+resid]) ----------------
// BM x 128 tile, BK=64, global_load_lds staging with source-XOR swizzle.
template <int EPI, int BM>
__global__ __launch_bounds__(256) void gemm_nt_kernel(
        const bf16_t* __restrict__ A, const bf16_t* __restrict__ W,
        const float* __restrict__ bias, void* __restrict__ outp,
        const float* __restrict__ resid, int M, int N, int K) {
    constexpr int MF = BM / 32;           // m-frags per wave
    __shared__ bf16_t As[BM * 64];
    __shared__ bf16_t Bs[128 * 64];
    int nbx = N >> 7;
    int cpx = gridDim.x >> 3;
    int bid = blockIdx.x;
    int tile = (bid & 7) * cpx + (bid >> 3);
    int bx = tile % nbx, by = tile / nbx;
    int m0 = by * BM, n0 = bx * 128;
    int t = threadIdx.x, l = t & 63, wid = t >> 6;
    int wm = (wid >> 1) * (BM / 2), wn = (wid & 1) * 64;
    int lr = l & 15, lg = l >> 4;

    f32x4 acc[MF][4] = {};
    for (int k0 = 0; k0 < K; k0 += 64) {
        #pragma unroll
        for (int i = 0; i < BM / 32; ++i) {
            int c = t + i * 256;
            int row = c >> 3, cc = c & 7;
            int col = (cc ^ (row & 7)) << 3;
            gload_lds16(A + (size_t)(m0 + row) * K + k0 + col, &As[c * 8]);
        }
        #pragma unroll
        for (int i = 0; i < 4; ++i) {
            int c = t + i * 256;
            int row = c >> 3, cc = c & 7;
            int col = (cc ^ (row & 7)) << 3;
            gload_lds16(W + (size_t)(n0 + row) * K + k0 + col, &Bs[c * 8]);
        }
        __syncthreads();
        #pragma unroll
        for (int s = 0; s < 2; ++s) {
            int xo = ((s * 4 + lg) ^ (lr & 7)) << 3;
            bf16x8 af[MF], bfr[4];
            #pragma unroll
            for (int mf = 0; mf < MF; ++mf)
                af[mf] = *reinterpret_cast<const bf16x8*>(&As[(wm + mf * 16 + lr) * 64 + xo]);
            #pragma unroll
            for (int nf = 0; nf < 4; ++nf)
                bfr[nf] = *reinterpret_cast<const bf16x8*>(&Bs[(wn + nf * 16 + lr) * 64 + xo]);
            #pragma unroll
            for (int mf = 0; mf < MF; ++mf) {
                #pragma unroll
                for (int nf = 0; nf < 4; ++nf)
                    acc[mf][nf] = __builtin_amdgcn_mfma_f32_16x16x32_bf16(af[mf], bfr[nf], acc[mf][nf], 0, 0, 0);
            }
        }
        __syncthreads();
    }
    #pragma unroll
    for (int mf = 0; mf < MF; ++mf) {
        #pragma unroll
        for (int r = 0; r < 4; ++r) {
            int row = m0 + wm + mf * 16 + lg * 4 + r;
            #pragma unroll
            for (int nf = 0; nf < 4; ++nf) {
                int col = n0 + wn + nf * 16 + lr;
                float v = acc[mf][nf][r] + bias[col];
                if (EPI == 0) {
                    reinterpret_cast<bf16_t*>(outp)[(size_t)row * N + col] = (bf16_t)v;
                } else {
                    size_t idx = (size_t)row * N + col;
                    reinterpret_cast<float*>(outp)[idx] = v + resid[idx];
                }
            }
        }
    }
}

// ---------------- V transpose: qkv V-part -> vT[b][h][d][k'] with k' = sigma(k) ----------------
// sigma(k): k' bits (k5,k3,k2,k4,k1,k0). Makes attn's PV B-frags contiguous 16B loads.
__global__ __launch_bounds__(256) void vtrans_kernel(const bf16_t* __restrict__ qkv,
                                                     bf16_t* __restrict__ vT) {
    __shared__ bf16_t tile[64 * 72];   // [s][d], stride 72
    int t = threadIdx.x;
    int kt = blockIdx.x & 15, bh = blockIdx.x >> 4;
    const bf16_t* src = qkv + ((size_t)(bh >> 4) * 1024 + kt * 64) * 3072 + 2048 + (bh & 15) * 64;
    #pragma unroll
    for (int i = 0; i < 2; ++i) {
        int c = t + i * 256;
        int s = c >> 3, dc = c & 7;
        bf16x8 v = *reinterpret_cast<const bf16x8*>(src + (size_t)s * 3072 + dc * 8);
        *reinterpret_cast<bf16x8*>(&tile[s * 72 + dc * 8]) = v;
    }
    __syncthreads();
    #pragma unroll
    for (int i = 0; i < 2; ++i) {
        int c = t + i * 256;
        int d = c >> 3, kc = c & 7;
        bf16x8 o;
        #pragma unroll
        for (int j = 0; j < 8; ++j) {
            // s = sigma_inv(kc*8 + j)
            int s = (kc >> 2) * 32 + (j >> 2) * 16 + ((kc >> 1) & 1) * 8 + (kc & 1) * 4 + (j & 3);
            o[j] = tile[s * 72 + d];
        }
        *reinterpret_cast<bf16x8*>(vT + ((size_t)bh * 64 + d) * 1024 + kt * 64 + kc * 8) = o;
    }
}

// ---------------- flash attention, v6: LDS-free, barrier-free ----------------
// K/V tiles are L2/L1-resident (XCD swizzle pins a (b,h)'s q-tiles to one XCD).
// K-frags: direct 16B global loads from qkv (contiguous along d).
// V-frags: direct 16B global loads from vT (contiguous along sigma-permuted k).
// P stays in registers (swapped QK^T, v5); prefetch next tile's frags during compute.
__global__ __launch_bounds__(256, 2) void attn_kernel(const bf16_t* __restrict__ qkv,
                                                      const bf16_t* __restrict__ vT,
                                                      bf16_t* __restrict__ o) {
    int bid = blockIdx.x;
    int tile = (bid & 7) * 64 + (bid >> 3);
    int qt = tile & 7, bh = tile >> 3;
    int hh = bh & 15;
    int t = threadIdx.x, l = t & 63, wid = t >> 6;
    int lr = l & 15, lg = l >> 4;
    const bf16_t* base = qkv + (size_t)(bh >> 4) * 1024 * 3072;

    // Q fragments (B-operand of swapped QK^T), pre-scaled by log2(e)/64
    bf16x8 qf[2][2];
    #pragma unroll
    for (int s = 0; s < 2; ++s) {
        int qrow = qt * 128 + wid * 32 + s * 16 + lr;
        const bf16_t* qp = base + (size_t)qrow * 3072 + hh * 64;
        bf16x8 q0 = *reinterpret_cast<const bf16x8*>(qp + lg * 8);
        bf16x8 q1 = *reinterpret_cast<const bf16x8*>(qp + 32 + lg * 8);
        #pragma unroll
        for (int j = 0; j < 8; ++j) {
            qf[s][0][j] = (bf16_t)((float)q0[j] * 0.02254211001f);
            qf[s][1][j] = (bf16_t)((float)q1[j] * 0.02254211001f);
        }
    }

    // per-lane frag base pointers
    const bf16_t* kp0 = base + 1024 + hh * 64 + (size_t)lr * 3072 + lg * 8;  // + (kt*64+f*16)*3072 + m*32
    const bf16_t* vp0 = vT + ((size_t)bh * 64 + lr) * 1024 + lg * 8;         // + nf*16*1024 + kt*64 + m*32

    f32x4 acc[2][4] = {};
    float den[2] = {0.f, 0.f};

    bf16x8 kf[4][2], vf[4][2];
    #pragma unroll
    for (int f = 0; f < 4; ++f) {
        kf[f][0] = *reinterpret_cast<const bf16x8*>(kp0 + (size_t)f * 16 * 3072);
        kf[f][1] = *reinterpret_cast<const bf16x8*>(kp0 + (size_t)f * 16 * 3072 + 32);
    }
    #pragma unroll
    for (int nf = 0; nf < 4; ++nf) {
        vf[nf][0] = *reinterpret_cast<const bf16x8*>(vp0 + (size_t)nf * 16384);
        vf[nf][1] = *reinterpret_cast<const bf16x8*>(vp0 + (size_t)nf * 16384 + 32);
    }

    #pragma unroll 2
    for (int kt = 0; kt < 16; ++kt) {
        // swapped QK^T: sc[s][f][r] = S[q = s*16+lr][k = f*16+lg*4+r] (pre-scaled)
        f32x4 sc[2][4];
        #pragma unroll
        for (int f = 0; f < 4; ++f) {
            #pragma unroll
            for (int s = 0; s < 2; ++s) {
                f32x4 z = {0.f, 0.f, 0.f, 0.f};
                z = __builtin_amdgcn_mfma_f32_16x16x32_bf16(kf[f][0], qf[s][0], z, 0, 0, 0);
                z = __builtin_amdgcn_mfma_f32_16x16x32_bf16(kf[f][1], qf[s][1], z, 0, 0, 0);
                sc[s][f] = z;
            }
        }
        // prefetch next K tile (kf regs are dead now; latency hidden by softmax+PV)
        if (kt < 15) {
            const bf16_t* kp = kp0 + (size_t)(kt + 1) * 64 * 3072;
            #pragma unroll
            for (int f = 0; f < 4; ++f) {
                kf[f][0] = *reinterpret_cast<const bf16x8*>(kp + (size_t)f * 16 * 3072);
                kf[f][1] = *reinterpret_cast<const bf16x8*>(kp + (size_t)f * 16 * 3072 + 32);
            }
        }

        // softmax numerator in-register; build PV A-frags: pa[s][m][j] = p[2m+(j>>2)][j&3]
        bf16x8 pa[2][2];
        #pragma unroll
        for (int s = 0; s < 2; ++s) {
            float p[4][4];
            #pragma unroll
            for (int f = 0; f < 4; ++f) {
                #pragma unroll
                for (int r = 0; r < 4; ++r) {
                    p[f][r] = exp2f(sc[s][f][r]);
                    den[s] += p[f][r];
                }
            }
            #pragma unroll
            for (int m = 0; m < 2; ++m) {
                #pragma unroll
                for (int j = 0; j < 8; ++j)
                    pa[s][m][j] = (bf16_t)p[2 * m + (j >> 2)][j & 3];
            }
        }

        // PV: acc[s][nf] += pa . vf
        #pragma unroll
        for (int nf = 0; nf < 4; ++nf) {
            #pragma unroll
            for (int s = 0; s < 2; ++s) {
                acc[s][nf] = __builtin_amdgcn_mfma_f32_16x16x32_bf16(pa[s][0], vf[nf][0], acc[s][nf], 0, 0, 0);
                acc[s][nf] = __builtin_amdgcn_mfma_f32_16x16x32_bf16(pa[s][1], vf[nf][1], acc[s][nf], 0, 0, 0);
            }
        }
        // prefetch next V tile (vf regs dead; latency hidden by next QK^T+softmax)
        if (kt < 15) {
            const bf16_t* vp = vp0 + (kt + 1) * 64;
            #pragma unroll
            for (int nf = 0; nf < 4; ++nf) {
                vf[nf][0] = *reinterpret_cast<const bf16x8*>(vp + (size_t)nf * 16384);
                vf[nf][1] = *reinterpret_cast<const bf16x8*>(vp + (size_t)nf * 16384 + 32);
            }
        }
    }

    // denominators: lane holds partials for q = lr; reduce over lane groups, redistribute
    float rs[2][4];
    #pragma unroll
    for (int s = 0; s < 2; ++s) {
        float v = den[s];
        v += __shfl_xor(v, 16, 64);
        v += __shfl_xor(v, 32, 64);
        #pragma unroll
        for (int r = 0; r < 4; ++r)
            rs[s][r] = 1.f / __shfl(v, (l & 48) | (lg * 4 + r), 64);
    }

    size_t obase = ((size_t)bh * 1024 + qt * 128 + wid * 32) * 64;
    #pragma unroll
    for (int s = 0; s < 2; ++s) {
        #pragma unroll
        for (int nf = 0; nf < 4; ++nf) {
            #pragma unroll
            for (int r = 0; r < 4; ++r) {
                int q = s * 16 + lg * 4 + r;
                int d = nf * 16 + lr;
                o[obase + q * 64 + d] = (bf16_t)(acc[s][nf][r] * rs[s][r]);
            }
        }
    }
}

extern "C" void kernel_launch(void* const* d_in, const int* in_sizes, int n_in,
                              void* d_out, int out_size, void* d_ws, size_t ws_size,
                              hipStream_t stream) {
    const float* x     = (const float*)d_in[0];
    const float* gn_w  = (const float*)d_in[1];
    const float* gn_b  = (const float*)d_in[2];
    const float* w_qkv = (const float*)d_in[3];
    const float* b_qkv = (const float*)d_in[4];
    const float* w_out = (const float*)d_in[5];
    const float* b_out = (const float*)d_in[6];
    float* out = (float*)d_out;

    bf16_t* h      = (bf16_t*)d_ws;                  // 8 MiB; dead after GEMM1 -> reused as vT
    bf16_t* wqkv_b = h + (size_t)4096 * 1024;
    bf16_t* wout_b = wqkv_b + (size_t)3072 * 1024;
    bf16_t* qkvb   = wout_b + (size_t)1024 * 1024;
    bf16_t* ob     = qkvb + (size_t)4096 * 3072;
    bf16_t* vT     = h;                              // alias: h is dead after GEMM1

    const int n1_4 = 3072 * 1024 / 4, ntot_4 = n1_4 + 1024 * 1024 / 4;
    cvt_bf16_kernel<<<(ntot_4 + 255) / 256, 256, 0, stream>>>(w_qkv, w_out, wqkv_b, wout_b, n1_4, ntot_4);
    groupnorm_kernel<<<128, 256, 0, stream>>>(x, gn_w, gn_b, h);
    gemm_nt_kernel<0, 128><<<768, 256, 0, stream>>>(h, wqkv_b, b_qkv, (void*)qkvb, nullptr, 4096, 3072, 1024);
    vtrans_kernel<<<1024, 256, 0, stream>>>(qkvb, vT);
    attn_kernel<<<512, 256, 0, stream>>>(qkvb, vT, ob);
    gemm_nt_kernel<1, 64><<<512, 256, 0, stream>>>(ob, wout_b, b_out, (void*)out, x, 4096, 1024, 1024);
}

// Round 7
// 120.795 us; speedup vs baseline: 1.1961x; 1.1961x over previous
//
#include <hip/hip_runtime.h>

typedef __bf16 bf16_t;
typedef bf16_t bf16x8 __attribute__((ext_vector_type(8)));
typedef bf16_t bf16x4 __attribute__((ext_vector_type(4)));
typedef float f32x4 __attribute__((ext_vector_type(4)));

__device__ __forceinline__ void gload_lds16(const bf16_t* g, bf16_t* l) {
    __builtin_amdgcn_global_load_lds(
        (const __attribute__((address_space(1))) void*)g,
        (__attribute__((address_space(3))) void*)l, 16, 0, 0);
}

// ---------------- fp32 -> bf16 convert (both weight matrices, one launch) ----------------
__global__ __launch_bounds__(256) void cvt_bf16_kernel(const float* __restrict__ in1,
                                                       const float* __restrict__ in2,
                                                       bf16_t* __restrict__ out1,
                                                       bf16_t* __restrict__ out2,
                                                       int n1_4, int ntot_4) {
    int i = blockIdx.x * 256 + threadIdx.x;
    if (i >= ntot_4) return;
    const float* in = (i < n1_4) ? in1 : in2;
    bf16_t* out = (i < n1_4) ? out1 : out2;
    int j = (i < n1_4) ? i : i - n1_4;
    float4 v = reinterpret_cast<const float4*>(in)[j];
    bf16x4 o;
    o[0] = (bf16_t)v.x; o[1] = (bf16_t)v.y; o[2] = (bf16_t)v.z; o[3] = (bf16_t)v.w;
    *reinterpret_cast<bf16x4*>(out + (size_t)j * 4) = o;
}

// ---------------- GroupNorm over dim1 groups ----------------
__global__ __launch_bounds__(256) void groupnorm_kernel(const float* __restrict__ x,
        const float* __restrict__ gw, const float* __restrict__ gb,
        bf16_t* __restrict__ h) {
    int bg = blockIdx.x;
    int batch = bg >> 5, g = bg & 31;
    const float* xp = x + ((size_t)batch * 1024 + g * 32) * 1024;
    float s = 0.f, s2 = 0.f;
    for (int i = threadIdx.x; i < 8192; i += 256) {
        float4 v = reinterpret_cast<const float4*>(xp)[i];
        s  += v.x + v.y + v.z + v.w;
        s2 += v.x*v.x + v.y*v.y + v.z*v.z + v.w*v.w;
    }
    #pragma unroll
    for (int o = 32; o >= 1; o >>= 1) {
        s  += __shfl_down(s, o, 64);
        s2 += __shfl_down(s2, o, 64);
    }
    __shared__ float ps[4], ps2[4];
    __shared__ float stat[2];
    if ((threadIdx.x & 63) == 0) { ps[threadIdx.x >> 6] = s; ps2[threadIdx.x >> 6] = s2; }
    __syncthreads();
    if (threadIdx.x == 0) {
        float S  = ps[0] + ps[1] + ps[2] + ps[3];
        float S2 = ps2[0] + ps2[1] + ps2[2] + ps2[3];
        float mu  = S * (1.f / 32768.f);
        float var = S2 * (1.f / 32768.f) - mu * mu;
        stat[0] = mu; stat[1] = rsqrtf(var + 1e-6f);
    }
    __syncthreads();
    float mu = stat[0], rs = stat[1];
    bf16_t* hp = h + ((size_t)batch * 1024 + g * 32) * 1024;
    for (int i = threadIdx.x; i < 8192; i += 256) {
        float4 v = reinterpret_cast<const float4*>(xp)[i];
        int row = i >> 8;
        float a = rs * gw[g * 32 + row];
        float b = gb[g * 32 + row] - mu * a;
        bf16x4 o;
        o[0] = (bf16_t)(v.x * a + b); o[1] = (bf16_t)(v.y * a + b);
        o[2] = (bf16_t)(v.z * a + b); o[3] = (bf16_t)(v.w * a + b);
        *reinterpret_cast<bf16x4*>(hp + (size_t)i * 4) = o;
    }
}

// ---------------- 256x256 8-phase bf16 GEMM: C[M,N] = A[M,K] @ W[N,K]^T + bias ----------------
// 512 thr (8 waves, 2M x 4N), BK=64, LDS 128 KiB (2 dbuf x 2 half x 128x64 x A,B).
// Per K-tile: 4 quadrant-phases of 16 MFMA; need-ordered staging A0,B0,B1,A1 of tile t+1
// -> uniform counted s_waitcnt vmcnt(4); last tile peeled with vmcnt(0) drain.
__global__ __launch_bounds__(512, 2) void gemm256_kernel(
        const bf16_t* __restrict__ A, const bf16_t* __restrict__ W,
        const float* __restrict__ bias, bf16_t* __restrict__ outp,
        int M, int N, int K) {
    __shared__ bf16_t As[2][2][128 * 64];
    __shared__ bf16_t Bs[2][2][128 * 64];
    int nbx = N >> 8;
    int cpx = gridDim.x >> 3;
    int bid = blockIdx.x;
    int tile = (bid & 7) * cpx + (bid >> 3);
    int bx = tile % nbx, by = tile / nbx;
    int m0 = by * 256, n0 = bx * 256;
    int t = threadIdx.x, l = t & 63, wid = t >> 6;
    int lr = l & 15, lg = l >> 4;
    int wm = (wid >> 2) * 128, wn = (wid & 3) * 64;
    int ah = wid >> 2;            // A half this wave reads
    int bh = (wid & 3) >> 1;      // B half this wave reads
    int bnl = wn & 64;            // base col within B half

    // staging chunks: 1024 chunks of 16B per half-tile, 2 per thread
    int c0 = t, c1 = t + 512;
    int r0 = c0 >> 3, col0 = (((c0 & 7) ^ (r0 & 7)) << 3);
    int r1 = c1 >> 3, col1 = (((c1 & 7) ^ (r1 & 7)) << 3);

    f32x4 acc[8][4] = {};

#define STAGE_A(slot, hf, kt) { \
        const bf16_t* _s = A + (size_t)(m0 + (hf) * 128) * K + (kt) * 64; \
        gload_lds16(_s + (size_t)r0 * K + col0, &As[slot][hf][c0 * 8]); \
        gload_lds16(_s + (size_t)r1 * K + col1, &As[slot][hf][c1 * 8]); }
#define STAGE_B(slot, hf, kt) { \
        const bf16_t* _s = W + (size_t)(n0 + (hf) * 128) * K + (kt) * 64; \
        gload_lds16(_s + (size_t)r0 * K + col0, &Bs[slot][hf][c0 * 8]); \
        gload_lds16(_s + (size_t)r1 * K + col1, &Bs[slot][hf][c1 * 8]); }
#define LOAD_AF(mh) \
        _Pragma("unroll") \
        for (int i = 0; i < 4; ++i) { \
            int row = (mh) * 64 + i * 16 + lr; \
            _Pragma("unroll") \
            for (int kk = 0; kk < 2; ++kk) \
                afr[i][kk] = *reinterpret_cast<const bf16x8*>( \
                    &As[cur][ah][row * 64 + (((kk * 4 + lg) ^ (row & 7)) << 3)]); }
#define LOAD_BF(dst, nh) \
        _Pragma("unroll") \
        for (int j = 0; j < 2; ++j) { \
            int col = bnl + (nh) * 32 + j * 16 + lr; \
            _Pragma("unroll") \
            for (int kk = 0; kk < 2; ++kk) \
                dst[j][kk] = *reinterpret_cast<const bf16x8*>( \
                    &Bs[cur][bh][col * 64 + (((kk * 4 + lg) ^ (col & 7)) << 3)]); }
#define MFMA_Q(mh, nh, bfr) \
        __builtin_amdgcn_s_setprio(1); \
        _Pragma("unroll") \
        for (int i = 0; i < 4; ++i) \
            _Pragma("unroll") \
            for (int j = 0; j < 2; ++j) \
                _Pragma("unroll") \
                for (int kk = 0; kk < 2; ++kk) \
                    acc[(mh) * 4 + i][(nh) * 2 + j] = __builtin_amdgcn_mfma_f32_16x16x32_bf16( \
                        afr[i][kk], bfr[j][kk], acc[(mh) * 4 + i][(nh) * 2 + j], 0, 0, 0); \
        __builtin_amdgcn_s_setprio(0);

    // prologue: stage tile 0 into slot 0, need-order A0,B0,B1,A1
    STAGE_A(0, 0, 0) STAGE_B(0, 0, 0) STAGE_B(0, 1, 0) STAGE_A(0, 1, 0)
    asm volatile("s_waitcnt vmcnt(0)" ::: "memory");
    __builtin_amdgcn_s_barrier();

    const int NT = K >> 6;
    for (int kt = 0; kt < NT - 1; ++kt) {
        int cur = kt & 1, nxt = cur ^ 1;
        bf16x8 afr[4][2], bf0[2][2], bf1[2][2];
        // phase 0: quadrant (m-half 0, n-half 0); stage next A0
        LOAD_AF(0) LOAD_BF(bf0, 0)
        STAGE_A(nxt, 0, kt + 1)
        __builtin_amdgcn_s_barrier();
        MFMA_Q(0, 0, bf0)
        asm volatile("s_waitcnt vmcnt(4)" ::: "memory");
        __builtin_amdgcn_s_barrier();
        // phase 1: (mh0, nh1); stage next B0
        LOAD_BF(bf1, 1)
        STAGE_B(nxt, 0, kt + 1)
        __builtin_amdgcn_s_barrier();
        MFMA_Q(0, 1, bf1)
        asm volatile("s_waitcnt vmcnt(4)" ::: "memory");
        __builtin_amdgcn_s_barrier();
        // phase 2: (mh1, nh1); stage next B1
        LOAD_AF(1)
        STAGE_B(nxt, 1, kt + 1)
        __builtin_amdgcn_s_barrier();
        MFMA_Q(1, 1, bf1)
        __builtin_amdgcn_s_barrier();
        // phase 3: (mh1, nh0) with held bf0; stage next A1
        STAGE_A(nxt, 1, kt + 1)
        __builtin_amdgcn_s_barrier();
        MFMA_Q(1, 0, bf0)
        asm volatile("s_waitcnt vmcnt(4)" ::: "memory");
        __builtin_amdgcn_s_barrier();
    }
    // peeled last tile: drain, then compute (no staging, no counted waits)
    {
        int cur = (NT - 1) & 1;
        asm volatile("s_waitcnt vmcnt(0)" ::: "memory");
        __builtin_amdgcn_s_barrier();
        bf16x8 afr[4][2], bf0[2][2], bf1[2][2];
        LOAD_AF(0) LOAD_BF(bf0, 0) LOAD_BF(bf1, 1)
        MFMA_Q(0, 0, bf0)
        MFMA_Q(0, 1, bf1)
        LOAD_AF(1)
        MFMA_Q(1, 1, bf1)
        MFMA_Q(1, 0, bf0)
    }

    #pragma unroll
    for (int mf = 0; mf < 8; ++mf) {
        #pragma unroll
        for (int r = 0; r < 4; ++r) {
            int row = m0 + wm + mf * 16 + lg * 4 + r;
            #pragma unroll
            for (int nf = 0; nf < 4; ++nf) {
                int col = n0 + wn + nf * 16 + lr;
                outp[(size_t)row * N + col] = (bf16_t)(acc[mf][nf][r] + bias[col]);
            }
        }
    }
#undef STAGE_A
#undef STAGE_B
#undef LOAD_AF
#undef LOAD_BF
#undef MFMA_Q
}

// ---------------- bf16 MFMA GEMM (m97 structure): C = A @ W^T (+bias[,+resid]) ----------------
template <int EPI, int BM>
__global__ __launch_bounds__(256) void gemm_nt_kernel(
        const bf16_t* __restrict__ A, const bf16_t* __restrict__ W,
        const float* __restrict__ bias, void* __restrict__ outp,
        const float* __restrict__ resid, int M, int N, int K) {
    constexpr int MF = BM / 32;
    __shared__ bf16_t As[BM * 64];
    __shared__ bf16_t Bs[128 * 64];
    int nbx = N >> 7;
    int cpx = gridDim.x >> 3;
    int bid = blockIdx.x;
    int tile = (bid & 7) * cpx + (bid >> 3);
    int bx = tile % nbx, by = tile / nbx;
    int m0 = by * BM, n0 = bx * 128;
    int t = threadIdx.x, l = t & 63, wid = t >> 6;
    int wm = (wid >> 1) * (BM / 2), wn = (wid & 1) * 64;
    int lr = l & 15, lg = l >> 4;

    f32x4 acc[MF][4] = {};
    for (int k0 = 0; k0 < K; k0 += 64) {
        #pragma unroll
        for (int i = 0; i < BM / 32; ++i) {
            int c = t + i * 256;
            int row = c >> 3, cc = c & 7;
            int col = (cc ^ (row & 7)) << 3;
            gload_lds16(A + (size_t)(m0 + row) * K + k0 + col, &As[c * 8]);
        }
        #pragma unroll
        for (int i = 0; i < 4; ++i) {
            int c = t + i * 256;
            int row = c >> 3, cc = c & 7;
            int col = (cc ^ (row & 7)) << 3;
            gload_lds16(W + (size_t)(n0 + row) * K + k0 + col, &Bs[c * 8]);
        }
        __syncthreads();
        #pragma unroll
        for (int s = 0; s < 2; ++s) {
            int xo = ((s * 4 + lg) ^ (lr & 7)) << 3;
            bf16x8 af[MF], bfr[4];
            #pragma unroll
            for (int mf = 0; mf < MF; ++mf)
                af[mf] = *reinterpret_cast<const bf16x8*>(&As[(wm + mf * 16 + lr) * 64 + xo]);
            #pragma unroll
            for (int nf = 0; nf < 4; ++nf)
                bfr[nf] = *reinterpret_cast<const bf16x8*>(&Bs[(wn + nf * 16 + lr) * 64 + xo]);
            #pragma unroll
            for (int mf = 0; mf < MF; ++mf) {
                #pragma unroll
                for (int nf = 0; nf < 4; ++nf)
                    acc[mf][nf] = __builtin_amdgcn_mfma_f32_16x16x32_bf16(af[mf], bfr[nf], acc[mf][nf], 0, 0, 0);
            }
        }
        __syncthreads();
    }
    #pragma unroll
    for (int mf = 0; mf < MF; ++mf) {
        #pragma unroll
        for (int r = 0; r < 4; ++r) {
            int row = m0 + wm + mf * 16 + lg * 4 + r;
            #pragma unroll
            for (int nf = 0; nf < 4; ++nf) {
                int col = n0 + wn + nf * 16 + lr;
                float v = acc[mf][nf][r] + bias[col];
                if (EPI == 0) {
                    reinterpret_cast<bf16_t*>(outp)[(size_t)row * N + col] = (bf16_t)v;
                } else {
                    size_t idx = (size_t)row * N + col;
                    reinterpret_cast<float*>(outp)[idx] = v + resid[idx];
                }
            }
        }
    }
}

// ---------------- flash attention, v5 (verified 43.3us): swapped QK^T + k-permuted V ----------------
__global__ __launch_bounds__(256, 2) void attn_kernel(const bf16_t* __restrict__ qkv,
                                                      bf16_t* __restrict__ o) {
    int bid = blockIdx.x;
    int tile = (bid & 7) * 64 + (bid >> 3);
    int qt = tile & 7, pair = tile >> 3;
    int hh = pair & 15, bb = pair >> 4;
    int t = threadIdx.x, l = t & 63, wid = t >> 6;
    int lr = l & 15, lg = l >> 4;
    const bf16_t* base = qkv + (size_t)bb * 1024 * 3072;

    __shared__ bf16_t Ks[2][64 * 64];
    __shared__ bf16_t Vs[2][64 * 64];

    bf16x8 qf[2][2];
    #pragma unroll
    for (int s = 0; s < 2; ++s) {
        int qrow = qt * 128 + wid * 32 + s * 16 + lr;
        const bf16_t* qp = base + (size_t)qrow * 3072 + hh * 64;
        bf16x8 q0 = *reinterpret_cast<const bf16x8*>(qp + lg * 8);
        bf16x8 q1 = *reinterpret_cast<const bf16x8*>(qp + 32 + lg * 8);
        #pragma unroll
        for (int j = 0; j < 8; ++j) {
            qf[s][0][j] = (bf16_t)((float)q0[j] * 0.02254211001f);
            qf[s][1][j] = (bf16_t)((float)q1[j] * 0.02254211001f);
        }
    }

    int sk0 = t >> 3, sch = t & 7;
    const bf16_t* vgp = base + 2048 + hh * 64 + (size_t)sk0 * 3072 + sch * 8;
    const int kp = ((sk0 & 12) << 1) | ((sk0 & 16) >> 2) | (sk0 & 3);
    const int kch = kp >> 3, koff = kp & 7;

    int kro[4][2], vro[4][2];
    #pragma unroll
    for (int f = 0; f < 4; ++f) {
        #pragma unroll
        for (int s = 0; s < 2; ++s) {
            kro[f][s] = (f * 16 + lr) * 64 + (((s * 4 + lg) ^ (lr & 7)) << 3);
            vro[f][s] = (f * 16 + lr) * 64 + ((((s * 4 + lg) ^ (lr & 7) ^ ((f * 2 + (lr >> 3)) & 7))) << 3);
        }
    }

    f32x4 acc[2][4] = {};
    float den[2] = {0.f, 0.f};

    #pragma unroll
    for (int i = 0; i < 2; ++i) {
        int c = t + i * 256;
        int kr = c >> 3, cc = c & 7;
        gload_lds16(base + (size_t)kr * 3072 + 1024 + hh * 64 + ((cc ^ (kr & 7)) << 3), &Ks[0][c * 8]);
    }
    {
        bf16x8 v0 = *reinterpret_cast<const bf16x8*>(vgp);
        bf16x8 v1 = *reinterpret_cast<const bf16x8*>(vgp + (size_t)32 * 3072);
        #pragma unroll
        for (int j = 0; j < 8; ++j) {
            int d = sch * 8 + j;
            Vs[0][d * 64 + (((kch ^ j ^ sch) & 7) << 3) + koff] = v0[j];
            Vs[0][d * 64 + ((((kch + 4) ^ j ^ sch) & 7) << 3) + koff] = v1[j];
        }
    }
    __syncthreads();

    for (int kt = 0; kt < 16; ++kt) {
        int cur = kt & 1, nxt = cur ^ 1;
        bf16x8 v0, v1;
        if (kt < 15) {
            int krn = (kt + 1) * 64;
            #pragma unroll
            for (int i = 0; i < 2; ++i) {
                int c = t + i * 256;
                int kr = c >> 3, cc = c & 7;
                gload_lds16(base + (size_t)(krn + kr) * 3072 + 1024 + hh * 64 + ((cc ^ (kr & 7)) << 3),
                            &Ks[nxt][c * 8]);
            }
            v0 = *reinterpret_cast<const bf16x8*>(vgp + (size_t)krn * 3072);
            v1 = *reinterpret_cast<const bf16x8*>(vgp + (size_t)(krn + 32) * 3072);
        }

        f32x4 sc[2][4];
        #pragma unroll
        for (int f = 0; f < 4; ++f) {
            bf16x8 a0 = *reinterpret_cast<const bf16x8*>(&Ks[cur][kro[f][0]]);
            bf16x8 a1 = *reinterpret_cast<const bf16x8*>(&Ks[cur][kro[f][1]]);
            #pragma unroll
            for (int s = 0; s < 2; ++s) {
                f32x4 z = {0.f, 0.f, 0.f, 0.f};
                z = __builtin_amdgcn_mfma_f32_16x16x32_bf16(a0, qf[s][0], z, 0, 0, 0);
                z = __builtin_amdgcn_mfma_f32_16x16x32_bf16(a1, qf[s][1], z, 0, 0, 0);
                sc[s][f] = z;
            }
        }

        bf16x8 pa[2][2];
        #pragma unroll
        for (int s = 0; s < 2; ++s) {
            float p[4][4];
            #pragma unroll
            for (int f = 0; f < 4; ++f) {
                #pragma unroll
                for (int r = 0; r < 4; ++r) {
                    p[f][r] = exp2f(sc[s][f][r]);
                    den[s] += p[f][r];
                }
            }
            #pragma unroll
            for (int m = 0; m < 2; ++m) {
                #pragma unroll
                for (int j = 0; j < 8; ++j)
                    pa[s][m][j] = (bf16_t)p[2 * m + (j >> 2)][j & 3];
            }
        }

        if (kt < 15) {
            #pragma unroll
            for (int j = 0; j < 8; ++j) {
                int d = sch * 8 + j;
                Vs[nxt][d * 64 + (((kch ^ j ^ sch) & 7) << 3) + koff] = v0[j];
                Vs[nxt][d * 64 + ((((kch + 4) ^ j ^ sch) & 7) << 3) + koff] = v1[j];
            }
        }

        #pragma unroll
        for (int nf = 0; nf < 4; ++nf) {
            bf16x8 w0 = *reinterpret_cast<const bf16x8*>(&Vs[cur][vro[nf][0]]);
            bf16x8 w1 = *reinterpret_cast<const bf16x8*>(&Vs[cur][vro[nf][1]]);
            #pragma unroll
            for (int s = 0; s < 2; ++s) {
                acc[s][nf] = __builtin_amdgcn_mfma_f32_16x16x32_bf16(pa[s][0], w0, acc[s][nf], 0, 0, 0);
                acc[s][nf] = __builtin_amdgcn_mfma_f32_16x16x32_bf16(pa[s][1], w1, acc[s][nf], 0, 0, 0);
            }
        }
        __syncthreads();
    }

    float rs[2][4];
    #pragma unroll
    for (int s = 0; s < 2; ++s) {
        float v = den[s];
        v += __shfl_xor(v, 16, 64);
        v += __shfl_xor(v, 32, 64);
        #pragma unroll
        for (int r = 0; r < 4; ++r)
            rs[s][r] = 1.f / __shfl(v, (l & 48) | (lg * 4 + r), 64);
    }

    size_t obase = ((size_t)(bb * 16 + hh) * 1024 + qt * 128 + wid * 32) * 64;
    #pragma unroll
    for (int s = 0; s < 2; ++s) {
        #pragma unroll
        for (int nf = 0; nf < 4; ++nf) {
            #pragma unroll
            for (int r = 0; r < 4; ++r) {
                int q = s * 16 + lg * 4 + r;
                int d = nf * 16 + lr;
                o[obase + q * 64 + d] = (bf16_t)(acc[s][nf][r] * rs[s][r]);
            }
        }
    }
}

extern "C" void kernel_launch(void* const* d_in, const int* in_sizes, int n_in,
                              void* d_out, int out_size, void* d_ws, size_t ws_size,
                              hipStream_t stream) {
    const float* x     = (const float*)d_in[0];
    const float* gn_w  = (const float*)d_in[1];
    const float* gn_b  = (const float*)d_in[2];
    const float* w_qkv = (const float*)d_in[3];
    const float* b_qkv = (const float*)d_in[4];
    const float* w_out = (const float*)d_in[5];
    const float* b_out = (const float*)d_in[6];
    float* out = (float*)d_out;

    bf16_t* h      = (bf16_t*)d_ws;
    bf16_t* wqkv_b = h + (size_t)4096 * 1024;
    bf16_t* wout_b = wqkv_b + (size_t)3072 * 1024;
    bf16_t* qkvb   = wout_b + (size_t)1024 * 1024;
    bf16_t* ob     = qkvb + (size_t)4096 * 3072;

    const int n1_4 = 3072 * 1024 / 4, ntot_4 = n1_4 + 1024 * 1024 / 4;
    cvt_bf16_kernel<<<(ntot_4 + 255) / 256, 256, 0, stream>>>(w_qkv, w_out, wqkv_b, wout_b, n1_4, ntot_4);
    groupnorm_kernel<<<128, 256, 0, stream>>>(x, gn_w, gn_b, h);
    gemm256_kernel<<<192, 512, 0, stream>>>(h, wqkv_b, b_qkv, qkvb, 4096, 3072, 1024);
    attn_kernel<<<512, 256, 0, stream>>>(qkvb, ob);
    gemm_nt_kernel<1, 64><<<512, 256, 0, stream>>>(ob, wout_b, b_out, (void*)out, x, 4096, 1024, 1024);
}